// Round 4
// baseline (446.370 us; speedup 1.0000x reference)
//
#include <hip/hip_runtime.h>
#include <hip/hip_bf16.h>
#include <cstdint>
#include <cstddef>

typedef unsigned short u16;
typedef unsigned int u32;
typedef short v8s __attribute__((ext_vector_type(8)));   // 8 bf16 payloads (4 VGPRs)
typedef float v4f __attribute__((ext_vector_type(4)));
typedef __hip_bfloat16 bf16;

// B=4, N=1024, D=1024, H=8, DK=DV=128
#define PROJ_ELEMS  4194304ull        // 4096*1024
#define AT_ELEMS    33554432ull       // 4*8*1024*1024
#define INV_TEMP    0.08838834764831845f

#define GLOBAL_AS __attribute__((address_space(1)))
#define LDS_AS    __attribute__((address_space(3)))

__device__ __forceinline__ void store_out(float* p, float v) { *p = v; }
__device__ __forceinline__ void store_out(bf16* p, float v) { *p = __float2bfloat16(v); }

// load 8 contiguous fp32 elements, convert to bf16x8 fragment
__device__ __forceinline__ v8s load8f(const float* p) {
    const float4 a = *(const float4*)p;
    const float4 b = *(const float4*)(p + 4);
    v8s r;
    bf16 t;
    t = __float2bfloat16(a.x); r[0] = *(const short*)&t;
    t = __float2bfloat16(a.y); r[1] = *(const short*)&t;
    t = __float2bfloat16(a.z); r[2] = *(const short*)&t;
    t = __float2bfloat16(a.w); r[3] = *(const short*)&t;
    t = __float2bfloat16(b.x); r[4] = *(const short*)&t;
    t = __float2bfloat16(b.y); r[5] = *(const short*)&t;
    t = __float2bfloat16(b.z); r[6] = *(const short*)&t;
    t = __float2bfloat16(b.w); r[7] = *(const short*)&t;
    return r;
}

// ---------------------------------------------------------------------------
// MFMA GEMM core:  C[128x128 tile] = alpha * A[M,K] @ B[N,K]^T   (bf16 A/B)
// Staged via global_load_lds width=16 (m97 fast path), unpadded [128][32].
// ---------------------------------------------------------------------------
template <typename AT, typename OutT>
__device__ __forceinline__ void gemm_core(
    const AT* __restrict__ Ab, const u16* __restrict__ Bb, OutT* __restrict__ Cb,
    int K, int lda, int ldb, int ldc, float alpha, int m0, int n0)
{
    __shared__ __align__(16) u16 sA[128][32];
    __shared__ __align__(16) u16 sB[128][32];

    const int tid  = threadIdx.x;
    const int lane = tid & 63;
    const int wid  = tid >> 6;
    const int wm = (wid >> 1) * 64;
    const int wn = (wid & 1) * 64;
    const int quad = lane >> 4;
    const int l16  = lane & 15;

    v4f acc[4][4];
    #pragma unroll
    for (int i = 0; i < 4; ++i)
        #pragma unroll
        for (int j = 0; j < 4; ++j)
            acc[i][j] = (v4f){0.f, 0.f, 0.f, 0.f};

    for (int k0 = 0; k0 < K; k0 += 32) {
        #pragma unroll
        for (int it = 0; it < 2; ++it) {
            const int slot = tid + it * 256;
            const int row  = slot >> 2;
            const int cg   = (slot & 3) << 3;
            __builtin_amdgcn_global_load_lds(
                (const GLOBAL_AS void*)(Bb + (size_t)(n0 + row) * (size_t)ldb + (size_t)(k0 + cg)),
                (LDS_AS void*)((char*)&sB[0][0] + slot * 16), 16, 0, 0);
            if constexpr (sizeof(AT) == 2) {
                __builtin_amdgcn_global_load_lds(
                    (const GLOBAL_AS void*)((const u16*)Ab + (size_t)(m0 + row) * (size_t)lda + (size_t)(k0 + cg)),
                    (LDS_AS void*)((char*)&sA[0][0] + slot * 16), 16, 0, 0);
            } else {
                *(v8s*)&sA[row][cg] =
                    load8f((const float*)Ab + (size_t)(m0 + row) * (size_t)lda + (size_t)(k0 + cg));
            }
        }
        __syncthreads();

        v8s af[4], bfr[4];
        #pragma unroll
        for (int i = 0; i < 4; ++i) {
            af[i]  = *(const v8s*)&sA[wm + i * 16 + l16][quad * 8];
            bfr[i] = *(const v8s*)&sB[wn + i * 16 + l16][quad * 8];
        }
        #pragma unroll
        for (int i = 0; i < 4; ++i)
            #pragma unroll
            for (int j = 0; j < 4; ++j)
                acc[i][j] = __builtin_amdgcn_mfma_f32_16x16x32_bf16(af[i], bfr[j], acc[i][j], 0, 0, 0);
        __syncthreads();
    }

    // C/D layout (m89-verified): col = lane&15, row = quad*4 + reg
    #pragma unroll
    for (int i = 0; i < 4; ++i) {
        int rbase = m0 + wm + i * 16 + quad * 4;
        #pragma unroll
        for (int j = 0; j < 4; ++j) {
            int gcol = n0 + wn + j * 16 + l16;
            #pragma unroll
            for (int r = 0; r < 4; ++r)
                store_out(&Cb[(size_t)(rbase + r) * (size_t)ldc + (size_t)gcol],
                          acc[i][j][r] * alpha);
        }
    }
}

template <typename AT, typename OutT>
__global__ __launch_bounds__(256, 3)
void gemm_fast(const AT* __restrict__ A, const u16* __restrict__ B, OutT* __restrict__ C,
               int K, int lda, int ldb, int ldc, int batDiv,
               long long sAo, long long sAi, long long sBo, long long sBi,
               long long sCo, long long sCi, float alpha, int swz)
{
    const int z  = blockIdx.z;
    const int zo = z / batDiv;
    const int zi = z - zo * batDiv;
    int bx, by;
    if (swz) {
        // XCD-locality: blocks sharing an A row-panel (same by) land on one XCD.
        // requires gridDim.x == 8, gridDim.y == 32.
        const int flat = blockIdx.x + (blockIdx.y << 3);
        const int xcd = flat & 7, slt = flat >> 3;
        by = xcd + ((slt >> 3) << 3);
        bx = slt & 7;
    } else {
        bx = blockIdx.x; by = blockIdx.y;
    }
    gemm_core<AT, OutT>(A + (size_t)zo * (size_t)sAo + (size_t)zi * (size_t)sAi,
                        B + (size_t)zo * (size_t)sBo + (size_t)zi * (size_t)sBi,
                        C + (size_t)zo * (size_t)sCo + (size_t)zi * (size_t)sCi,
                        K, lda, ldb, ldc, alpha, by * 128, bx * 128);
}

// all five projections in one launch; XCD-locality swizzle groups the 8
// n-blocks sharing an A row-panel (plus the shared 2MB weight) on one XCD.
struct P5 { const u16* a[5]; };
__global__ __launch_bounds__(256, 3)
void gemm_proj5(P5 As, const u16* __restrict__ W, u16* __restrict__ C)
{
    const int fid = blockIdx.x + (blockIdx.y << 3) + (blockIdx.z << 8);
    const int xcd = fid & 7, s = fid >> 3;          // s in 0..159
    const int p = ((s >> 3) << 3) + xcd;            // pair index 0..159
    const int bx = s & 7;                           // n-tile
    const int by = p & 31;                          // m-tile (row panel)
    const int z  = p >> 5;                          // projection 0..4
    gemm_core<u16, bf16>(As.a[z], W + (size_t)z * 1048576ull,
                         (bf16*)(C + (size_t)z * PROJ_ELEMS),
                         1024, 1024, 1024, 1024, 1.f, by * 128, bx * 128);
}

// feature logits, split-K: grid (8 kc, 32 z); partial [z]128x128 over K=128
__global__ __launch_bounds__(256, 3)
void gemm_feat_sk(const u16* __restrict__ qfT, const u16* __restrict__ kfT, float* __restrict__ Fp)
{
    const int kc = blockIdx.x, z = blockIdx.y;
    gemm_core<u16, float>(qfT + (size_t)z * 131072ull + (size_t)kc * 128ull,
                          kfT + (size_t)z * 131072ull + (size_t)kc * 128ull,
                          Fp + ((size_t)kc * 32 + z) * 16384ull,
                          128, 1024, 1024, 128, INV_TEMP, 0, 0);
}

// ---------------------------------------------------------------------------
// fp32 -> bf16 unified converter + mask bit-pack:
// z 0..4 activations (2048 blocks), z 5..10 weights (512), z 11 mask (512).
// ---------------------------------------------------------------------------
struct CP11 { const float* p[11]; };

__global__ __launch_bounds__(256)
void cvt_all(CP11 ps, u16* __restrict__ actDst, u16* __restrict__ wDst,
             const int* __restrict__ mask, u32* __restrict__ mb)
{
    const int z = blockIdx.z;
    if (z == 11) {
        if (blockIdx.x >= 512) return;
        const int w = blockIdx.x * 256 + threadIdx.x;   // 131072 words
        const int* src = mask + (size_t)w * 32ull;
        u32 bits = 0;
        #pragma unroll
        for (int i = 0; i < 32; i += 4) {
            int4 v = *(const int4*)(src + i);
            bits |= (u32)(v.x != 0) << i;
            bits |= (u32)(v.y != 0) << (i + 1);
            bits |= (u32)(v.z != 0) << (i + 2);
            bits |= (u32)(v.w != 0) << (i + 3);
        }
        mb[w] = bits;
        return;
    }
    const int nblk = (z < 5) ? 2048 : 512;
    if (blockIdx.x >= nblk) return;
    const float* s = ps.p[z];
    u16* d = (z < 5) ? (actDst + (size_t)z * PROJ_ELEMS)
                     : (wDst + (size_t)(z - 5) * 1048576ull);
    const int i = (blockIdx.x * 256 + threadIdx.x) * 8;
    *(v8s*)(d + i) = load8f(s + i);
}

// ---------------------------------------------------------------------------
// Batched transpose of three projections: per z=(b*8+h) [1024 m][128 d] view
// -> [z][128 d][1024 m] contiguous.
// ---------------------------------------------------------------------------
struct T3 { const u16* in[3]; u16* out[3]; };
__global__ __launch_bounds__(256)
void transpose3(T3 t3)
{
    __shared__ u16 tile[32][33];
    const int sel = blockIdx.z >> 5;
    const int z   = blockIdx.z & 31;
    const int b = z >> 3, h = z & 7;
    const u16* ib = t3.in[sel] + (size_t)b * 1048576ull + (size_t)h * 128ull;
    u16* ob = t3.out[sel] + (size_t)z * 131072ull;
    const int m0 = blockIdx.x * 32;
    const int d0 = blockIdx.y * 32;
    const int tx = threadIdx.x;
    const int ty = threadIdx.y;
    #pragma unroll
    for (int i = 0; i < 4; ++i)
        tile[ty + i * 8][tx] = ib[(size_t)(m0 + ty + i * 8) * 1024ull + (size_t)(d0 + tx)];
    __syncthreads();
    #pragma unroll
    for (int i = 0; i < 4; ++i)
        ob[(size_t)(d0 + ty + i * 8) * 1024ull + (size_t)(m0 + tx)] = tile[tx][ty + i * 8];
}

// ---------------------------------------------------------------------------
// Fused attention v3: 64 Q-rows/block, KVBLK=64, 256 threads (4 waves),
// LDS 59 KB -> TWO blocks/CU (cross-block overlap hides barrier stalls).
//  - wave owns 16 rows; softmax stats pure in-register shuffles.
//  - 16 KV-tiles; K/V in a 2x16KB dbuf, counted prefetch a full iter ahead.
//  - pass B: 3 barriers/tile; V_nt staged at end of nt-1.
//  - fused out2 epilogue: pacc (P@V tile, complete per block) -> LDS (reuse
//    sQ), FT staged XOR-swizzled into the K/V buffer, 32 MFMA/wave -> o2.
// grid (16 m-tiles, 32 z) XCD-swizzled, block 256.
// ---------------------------------------------------------------------------
__global__ __launch_bounds__(256, 2)
void fused_attn(const u16* __restrict__ qt, const u16* __restrict__ kt,
                const u16* __restrict__ vvT, const u32* __restrict__ mb,
                const u16* __restrict__ FTg,
                float* __restrict__ oAT, u16* __restrict__ o2)
{
    __shared__ __align__(16) u16 sQ[4][64][32];        // resident Q tile, 16 KB
    __shared__ __align__(16) u16 sT2[2][8192];         // K/V staging dbuf, 32 KB
    __shared__ __align__(16) u16 sP[2][64][40];        // bf16 probs, padded, 10 KB
    __shared__ u32 smw[2][64][2];                      // mask words dbuf, 1 KB

    // XCD-locality remap: all 16 m-tiles of a z on one XCD (4 z per XCD).
    const int flat = blockIdx.x + (blockIdx.y << 4);
    const int xcd = flat & 7, s = flat >> 3;           // s in 0..63
    const int z  = xcd + ((s >> 4) << 3);
    const int m0 = (s & 15) << 6;

    const int b = z >> 3, h = z & 7;
    const u16* qb = qt + (size_t)b * 1048576ull + (size_t)h * 128ull;
    const u16* kb = kt + (size_t)b * 1048576ull + (size_t)h * 128ull;
    const u16* vb = vvT + (size_t)z * 131072ull;
    float* Ob = oAT + (size_t)z * 1048576ull;
    const u32* mbb = mb + (size_t)b * 32768ull;

    const int tid = threadIdx.x;
    const int lane = tid & 63, wid = tid >> 6;         // 4 waves
    const int quad = lane >> 4, l16 = lane & 15;
    const int wm = wid << 4;                           // wave's 16-row slice

    // ---- staging lambdas: issue-only; waits at call sites ----
    auto stK = [&](int nt, int buf) {                  // 4 x 16B per thread
        #pragma unroll
        for (int it = 0; it < 4; ++it) {
            const int s2 = tid + it * 256;             // 0..1023
            const int ks = s2 >> 8, row = (s2 >> 2) & 63, cg = (s2 & 3) << 3;
            __builtin_amdgcn_global_load_lds(
                (const GLOBAL_AS void*)(kb + (size_t)(nt * 64 + row) * 1024ull + ks * 32 + cg),
                (LDS_AS void*)((char*)&sT2[buf][0] + s2 * 16), 16, 0, 0);
        }
    };
    auto stV = [&](int nt, int buf) {                  // 4 x 16B per thread
        #pragma unroll
        for (int it = 0; it < 4; ++it) {
            const int s2 = tid + it * 256;
            const int ks2 = s2 >> 9, row = (s2 >> 2) & 127, cg = (s2 & 3) << 3;
            __builtin_amdgcn_global_load_lds(
                (const GLOBAL_AS void*)(vb + (size_t)row * 1024ull + nt * 64 + ks2 * 32 + cg),
                (LDS_AS void*)((char*)&sT2[buf][0] + s2 * 16), 16, 0, 0);
        }
    };
    auto stM = [&](int nt, int buf) {                  // 1 x 4B per thread (128 words, 2x dup)
        const int W = tid & 127;                       // row*2 + w
        __builtin_amdgcn_global_load_lds(
            (const GLOBAL_AS void*)(mbb + (size_t)(m0 + (W >> 1)) * 32ull + nt * 2 + (W & 1)),
            (LDS_AS void*)((char*)&smw[buf][0][0] + W * 4), 4, 0, 0);
    };

    // ---- prologue: Q (4) + K0 (4) + m0 (1) per thread in flight ----
    #pragma unroll
    for (int it = 0; it < 4; ++it) {
        const int s2 = tid + it * 256;
        const int ks = s2 >> 8, row = (s2 >> 2) & 63, cg = (s2 & 3) << 3;
        __builtin_amdgcn_global_load_lds(
            (const GLOBAL_AS void*)(qb + (size_t)(m0 + row) * 1024ull + ks * 32 + cg),
            (LDS_AS void*)((char*)&sQ[0][0][0] + s2 * 16), 16, 0, 0);
    }
    stK(0, 0); stM(0, 0);

    float Mreg[4], Lreg[4];                            // per-lane stats, 4 rows
    #pragma unroll
    for (int x = 0; x < 4; ++x) { Mreg[x] = -3.0e38f; Lreg[x] = 0.f; }

    // ---------------- PASS A: row max M and row sum L (16 tiles) ----------------
    int bufA = 0, mcur = 0;
    for (int nt = 0; nt < 16; ++nt) {
        stK((nt + 1) & 15, bufA ^ 1);                  // nt=15 stages K0 for pass B
        stM((nt + 1) & 15, mcur ^ 1);
        asm volatile("s_waitcnt vmcnt(5)" ::: "memory");   // K_nt + m_nt landed; 5 in flight
        __builtin_amdgcn_s_barrier();
        __builtin_amdgcn_sched_barrier(0);

        v4f acc[4];
        #pragma unroll
        for (int j = 0; j < 4; ++j)
            acc[j] = (v4f){0.f, 0.f, 0.f, 0.f};
        #pragma unroll
        for (int ks = 0; ks < 4; ++ks) {
            const v8s aq = *(const v8s*)&sQ[ks][wm + l16][quad * 8];
            v8s bk[4];
            #pragma unroll
            for (int j = 0; j < 4; ++j)
                bk[j] = *(const v8s*)&sT2[bufA][ks * 2048 + (j * 16 + l16) * 32 + quad * 8];
            #pragma unroll
            for (int j = 0; j < 4; ++j)
                acc[j] = __builtin_amdgcn_mfma_f32_16x16x32_bf16(aq, bk[j], acc[j], 0, 0, 0);
        }

        // in-register masked online stats
        #pragma unroll
        for (int r = 0; r < 4; ++r) {
            const int rowl = wm + quad * 4 + r;
            const u32 mw0 = smw[mcur][rowl][0];
            const u32 mw1 = smw[mcur][rowl][1];
            float sv[4];
            float tmax = -3.0e38f;
            #pragma unroll
            for (int j = 0; j < 4; ++j) {
                const u32 word = (j < 2) ? mw0 : mw1;
                const int bit = ((j & 1) << 4) + l16;
                float sc = acc[j][r] * INV_TEMP;
                sc = ((word >> bit) & 1u) ? sc : -1e9f;
                sv[j] = sc;
                tmax = fmaxf(tmax, sc);
            }
            #pragma unroll
            for (int m = 1; m <= 8; m <<= 1)
                tmax = fmaxf(tmax, __shfl_xor(tmax, m));
            const float Mo = Mreg[r];
            const float Mn = fmaxf(Mo, tmax);
            float t = 0.f;
            #pragma unroll
            for (int j = 0; j < 4; ++j)
                t += __expf(sv[j] - Mn);
            #pragma unroll
            for (int m = 1; m <= 8; m <<= 1)
                t += __shfl_xor(t, m);
            Lreg[r] = Lreg[r] * __expf(Mo - Mn) + t;
            Mreg[r] = Mn;
        }

        asm volatile("s_waitcnt lgkmcnt(0)" ::: "memory");
        __builtin_amdgcn_s_barrier();                  // sT2[bufA] free for restage
        __builtin_amdgcn_sched_barrier(0);
        bufA ^= 1; mcur ^= 1;
    }
    // after 16 flips: bufA == 0 holds K0 (in flight), mcur == 0 holds m0.

    const int BK = 0, BV = 1;
    stV(0, BV);                                        // V0 in flight

    float IL[4];
    #pragma unroll
    for (int x = 0; x < 4; ++x) IL[x] = 1.f / Lreg[x];

    v4f pacc[8];
    #pragma unroll
    for (int j = 0; j < 8; ++j)
        pacc[j] = (v4f){0.f, 0.f, 0.f, 0.f};

    // ---------------- PASS B: probs out + PV accumulate (16 tiles) ----------------
    for (int nt = 0; nt < 16; ++nt) {
        // K_nt, m_nt staged mid-iter nt-1; V_nt staged end of nt-1: all had a
        // full compute phase to land. Drain (stores included; they're old).
        asm volatile("s_waitcnt vmcnt(0)" ::: "memory");
        __builtin_amdgcn_s_barrier();
        __builtin_amdgcn_sched_barrier(0);

        v4f acc[4];
        #pragma unroll
        for (int j = 0; j < 4; ++j)
            acc[j] = (v4f){0.f, 0.f, 0.f, 0.f};
        #pragma unroll
        for (int ks = 0; ks < 4; ++ks) {
            const v8s aq = *(const v8s*)&sQ[ks][wm + l16][quad * 8];
            v8s bk[4];
            #pragma unroll
            for (int j = 0; j < 4; ++j)
                bk[j] = *(const v8s*)&sT2[BK][ks * 2048 + (j * 16 + l16) * 32 + quad * 8];
            #pragma unroll
            for (int j = 0; j < 4; ++j)
                acc[j] = __builtin_amdgcn_mfma_f32_16x16x32_bf16(aq, bk[j], acc[j], 0, 0, 0);
        }

        // probs: fp32 to oAT + bf16 into padded sP
        #pragma unroll
        for (int r = 0; r < 4; ++r) {
            const int rowl = wm + quad * 4 + r;
            const u32 mw0 = smw[mcur][rowl][0];
            const u32 mw1 = smw[mcur][rowl][1];
            float* orow = Ob + (size_t)(m0 + rowl) * 1024ull + nt * 64;
            #pragma unroll
            for (int j = 0; j < 4; ++j) {
                const u32 word = (j < 2) ? mw0 : mw1;
                const int bit = ((j & 1) << 4) + l16;
                float sc = acc[j][r] * INV_TEMP;
                sc = ((word >> bit) & 1u) ? sc : -1e9f;
                const float p = __expf(sc - Mreg[r]) * IL[r];
                orow[j * 16 + l16] = p;
                bf16 pb = __float2bfloat16(p);
                const int c = j * 16 + l16;
                sP[c >> 5][rowl][c & 31] = *(const u16*)&pb;
            }
        }

        asm volatile("s_waitcnt lgkmcnt(0)" ::: "memory");
        __builtin_amdgcn_s_barrier();                  // sP visible; all QK reads of BK done
        __builtin_amdgcn_sched_barrier(0);

        if (nt < 15) { stK(nt + 1, BK); stM(nt + 1, mcur ^ 1); }

        // PV: pacc[m][e] += P[m][k64] @ V^T ; V tile = vvT[e 128][k 64]
        #pragma unroll
        for (int ks2 = 0; ks2 < 2; ++ks2) {
            const v8s ap = *(const v8s*)&sP[ks2][wm + l16][quad * 8];
            v8s bv[8];
            #pragma unroll
            for (int j = 0; j < 8; ++j)
                bv[j] = *(const v8s*)&sT2[BV][ks2 * 4096 + (j * 16 + l16) * 32 + quad * 8];
            #pragma unroll
            for (int j = 0; j < 8; ++j)
                pacc[j] = __builtin_amdgcn_mfma_f32_16x16x32_bf16(ap, bv[j], pacc[j], 0, 0, 0);
        }

        asm volatile("s_waitcnt lgkmcnt(0)" ::: "memory");
        __builtin_amdgcn_s_barrier();                  // all PV reads of BV done
        __builtin_amdgcn_sched_barrier(0);

        if (nt < 15) stV(nt + 1, BV);
        mcur ^= 1;
    }

    // ---------------- fused out2 epilogue: o2 = (P@V) @ AF ----------------
    // sPV reuses sQ (16 KB, [4 ks][64][32]); sFT reuses sT2 (32 KB, XOR-swizzled).
    u16* sPVp = &sQ[0][0][0];
    u16* sFTp = &sT2[0][0];
    const u16* FTz = FTg + (size_t)z * 16384ull;

    #pragma unroll
    for (int j = 0; j < 8; ++j) {
        const int c = j * 16 + l16;
        #pragma unroll
        for (int r = 0; r < 4; ++r) {
            const int rowl = wm + quad * 4 + r;
            bf16 pb = __float2bfloat16(pacc[j][r]);
            sPVp[(c >> 5) * 2048 + rowl * 32 + (c & 31)] = *(const u16*)&pb;
        }
    }
    #pragma unroll
    for (int rep = 0; rep < 8; ++rep) {                // FT: 2048 groups of 8 u16
        const int grp = tid + rep * 256;
        const int row = grp >> 4;
        v8s v = *(const v8s*)(FTz + (size_t)grp * 8ull);
        *(v8s*)((char*)sFTp + ((grp * 16) ^ ((row & 7) << 4))) = v;
    }
    asm volatile("s_waitcnt lgkmcnt(0)" ::: "memory");
    __builtin_amdgcn_s_barrier();
    __builtin_amdgcn_sched_barrier(0);

    v4f o2a[8];
    #pragma unroll
    for (int j = 0; j < 8; ++j)
        o2a[j] = (v4f){0.f, 0.f, 0.f, 0.f};
    #pragma unroll
    for (int ks = 0; ks < 4; ++ks) {
        const v8s ap2 = *(const v8s*)&sPVp[ks * 2048 + (wm + l16) * 32 + quad * 8];
        #pragma unroll
        for (int j = 0; j < 8; ++j) {
            const int rowf = j * 16 + l16;
            const v8s bft = *(const v8s*)((char*)sFTp +
                ((rowf * 256 + ks * 64 + quad * 16) ^ ((rowf & 7) << 4)));
            o2a[j] = __builtin_amdgcn_mfma_f32_16x16x32_bf16(ap2, bft, o2a[j], 0, 0, 0);
        }
    }

    u16* o2B = o2 + (size_t)b * 1048576ull + (size_t)h * 128ull;
    #pragma unroll
    for (int j = 0; j < 8; ++j) {
        const int c = j * 16 + l16;
        #pragma unroll
        for (int r = 0; r < 4; ++r) {
            const int m = m0 + wm + quad * 4 + r;
            bf16 t = __float2bfloat16(o2a[j][r]);
            o2B[(size_t)m * 1024ull + c] = *(const u16*)&t;
        }
    }
}

// ---------------------------------------------------------------------------
// Feature softmax with split-K reduction: Fp [8 kc][32 z][128 d][128 e] ->
// softmax rows -> fp32 attn_feature output AND transposed bf16 FT[z][e][d].
// ---------------------------------------------------------------------------
__global__ __launch_bounds__(128)
void softmax_feat(const float* __restrict__ Fp, float* __restrict__ out_af, u16* __restrict__ FT)
{
    const int r = blockIdx.x;
    const int z = r >> 7, d = r & 127;
    const int e = threadIdx.x;
    float x = 0.f;
    #pragma unroll
    for (int kc = 0; kc < 8; ++kc)
        x += Fp[((size_t)kc * 32 + z) * 16384ull + (size_t)d * 128ull + e];
    float mx = x;
    #pragma unroll
    for (int o = 32; o; o >>= 1) mx = fmaxf(mx, __shfl_xor(mx, o));
    __shared__ float redm[2], reds[2];
    const int w = e >> 6;
    if ((e & 63) == 0) redm[w] = mx;
    __syncthreads();
    mx = fmaxf(redm[0], redm[1]);
    float ex = __expf(x - mx);
    float s = ex;
    #pragma unroll
    for (int o = 32; o; o >>= 1) s += __shfl_xor(s, o);
    if ((e & 63) == 0) reds[w] = s;
    __syncthreads();
    s = reds[0] + reds[1];
    float p = ex / s;
    out_af[(size_t)r * 128ull + e] = p;
    bf16 pb = __float2bfloat16(p);
    FT[(size_t)z * 16384ull + (size_t)e * 128ull + d] = *(const u16*)&pb;
}

// ---------------------------------------------------------------------------
// out = LayerNorm(fc + v) * gamma + beta ; one block per row; float4 loads
// ---------------------------------------------------------------------------
__global__ __launch_bounds__(256)
void resid_ln(const float* __restrict__ fc, const float* __restrict__ v,
              const float* __restrict__ gamma, const float* __restrict__ beta,
              float* __restrict__ out)
{
    const int r = blockIdx.x;
    const int t = threadIdx.x;
    const float4* fr = (const float4*)(fc + (size_t)r * 1024ull);
    const float4* vr = (const float4*)(v  + (size_t)r * 1024ull);
    float4 a = fr[t], b4 = vr[t];
    float4 x = {a.x + b4.x, a.y + b4.y, a.z + b4.z, a.w + b4.w};
    float s  = x.x + x.y + x.z + x.w;
    float s2 = x.x * x.x + x.y * x.y + x.z * x.z + x.w * x.w;
    #pragma unroll
    for (int o = 32; o; o >>= 1) { s += __shfl_xor(s, o); s2 += __shfl_xor(s2, o); }
    __shared__ float rs[4], rs2[4];
    const int w = t >> 6;
    if ((t & 63) == 0) { rs[w] = s; rs2[w] = s2; }
    __syncthreads();
    s  = rs[0] + rs[1] + rs[2] + rs[3];
    s2 = rs2[0] + rs2[1] + rs2[2] + rs2[3];
    const float mean = s * (1.f / 1024.f);
    const float var  = s2 * (1.f / 1024.f) - mean * mean;
    const float rstd = rsqrtf(var + 1e-6f);
    const float4 g = ((const float4*)gamma)[t];
    const float4 bb = ((const float4*)beta)[t];
    float4 o4 = {(x.x - mean) * rstd * g.x + bb.x,
                 (x.y - mean) * rstd * g.y + bb.y,
                 (x.z - mean) * rstd * g.z + bb.z,
                 (x.w - mean) * rstd * g.w + bb.w};
    ((float4*)(out + (size_t)r * 1024ull))[t] = o4;
}

// ---------------------------------------------------------------------------
extern "C" void kernel_launch(void* const* d_in, const int* in_sizes, int n_in,
                              void* d_out, int out_size, void* d_ws, size_t ws_size,
                              hipStream_t stream)
{
    (void)in_sizes; (void)n_in; (void)out_size; (void)ws_size;
    const float* q_time    = (const float*)d_in[0];
    const float* k_time    = (const float*)d_in[1];
    const float* q_feature = (const float*)d_in[2];
    const float* k_feature = (const float*)d_in[3];
    const float* v_in      = (const float*)d_in[4];
    const int*   mask      = (const int*)d_in[5];
    const float* w_qs_t    = (const float*)d_in[6];
    const float* w_ks_t    = (const float*)d_in[7];
    const float* w_qs_f    = (const float*)d_in[8];
    const float* w_ks_f    = (const float*)d_in[9];
    const float* w_vs      = (const float*)d_in[10];
    const float* w_fc      = (const float*)d_in[11];
    const float* gamma     = (const float*)d_in[12];
    const float* beta      = (const float*)d_in[13];

    // workspace layout (93 MB peak; liveness-aliased):
    //  0..40   act (5x8MB)              [dead after proj5]
    // 40..52   wbf (6x2MB; wfc 50..52 alive until fc)
    // 52..92   qt,kt,qf,kf,vv (5x8MB)   [qf,kf dead after transpose3; vv after transpose3;
    //                                    qt,kt dead after fused_attn]
    //  0..8    vvT    (aliases act)
    //  8..16   qfT
    // 16..24   kfT
    // 24..25   FT
    // 25..41   Fp (8x2MB fp32 partials)
    // 41..49   o2  (written by fused_attn epilogue; aliases dead wbf[41..49]/act)
    // 60..76   fc  (aliases dead kt,qf)
    // 92..92.5 mb  (mask bits, virgin region)
    char* ws = (char*)d_ws;
    const size_t MB = 1ull << 20;
    u16*   act = (u16*)(ws + 0  * MB);
    u16*   wbf = (u16*)(ws + 40 * MB);
    u16*   qt  = (u16*)(ws + 52 * MB);
    u16*   vvT = (u16*)(ws + 0  * MB);
    u16*   qfT = (u16*)(ws + 8  * MB);
    u16*   kfT = (u16*)(ws + 16 * MB);
    u16*   FT  = (u16*)(ws + 24 * MB);
    float* Fp  = (float*)(ws + 25 * MB);
    u16*   o2  = (u16*)(ws + 41 * MB);
    float* fc  = (float*)(ws + 60 * MB);
    u32*   mb  = (u32*)(ws + 92 * MB);
    u16*   kt  = qt + PROJ_ELEMS;
    u16*   qf  = kt + PROJ_ELEMS;
    u16*   kf  = qf + PROJ_ELEMS;
    u16*   vv  = kf + PROJ_ELEMS;
    u16*   wfc = wbf + 5ull * 1048576ull;

    float* out0 = (float*)d_out;
    float* oAT  = out0 + PROJ_ELEMS;              // attn_time [4,8,1024,1024] fp32
    float* oAF  = out0 + PROJ_ELEMS + AT_ELEMS;   // attn_feature [4,8,128,128] fp32

    const dim3 blk(256);

    // 0) fp32 -> bf16 conversions + mask bit-pack, one launch
    {
        CP11 ca;
        ca.p[0] = q_time; ca.p[1] = k_time; ca.p[2] = q_feature;
        ca.p[3] = k_feature; ca.p[4] = v_in;
        ca.p[5] = w_qs_t; ca.p[6] = w_ks_t; ca.p[7] = w_qs_f;
        ca.p[8] = w_ks_f; ca.p[9] = w_vs; ca.p[10] = w_fc;
        cvt_all<<<dim3(2048, 1, 12), blk, 0, stream>>>(ca, act, wbf, mask, mb);
    }

    // 1) five projections, one launch (XCD-swizzled)
    {
        P5 ps; for (int i = 0; i < 5; ++i) ps.a[i] = act + (size_t)i * PROJ_ELEMS;
        gemm_proj5<<<dim3(8, 32, 5), blk, 0, stream>>>(ps, wbf, qt);
    }

    // 2) transposes vv,qf,kf -> vvT,qfT,kfT
    {
        T3 t3; t3.in[0] = vv; t3.in[1] = qf; t3.in[2] = kf;
               t3.out[0] = vvT; t3.out[1] = qfT; t3.out[2] = kfT;
        transpose3<<<dim3(32, 4, 96), dim3(32, 8, 1), 0, stream>>>(t3);
    }

    // 3) feature logits (split-K x8) -> Fp partials
    gemm_feat_sk<<<dim3(8, 32), blk, 0, stream>>>(qfT, kfT, Fp);

    // 4) feature softmax (+split-K reduce) -> oAF fp32 + FT bf16
    softmax_feat<<<4096, 128, 0, stream>>>(Fp, oAF, FT);

    // 5) fused attention: logits+mask+softmax -> oAT fp32; (P@V)@AF -> o2 bf16
    fused_attn<<<dim3(16, 32), blk, 0, stream>>>(qt, kt, vvT, mb, FT, oAT, o2);

    // 6) fc: o2(bf16) @ w_fc(bf16)^T -> fp32 (XCD-swizzled)
    gemm_fast<<<dim3(8, 32, 1), blk, 0, stream>>>(o2, wfc, fc, 1024, 1024, 1024, 1024, 1,
        0LL, 0LL, 0LL, 0LL, 0LL, 0LL, 1.f, 1);

    // 7) residual + LayerNorm -> out0
    resid_ln<<<4096, 256, 0, stream>>>(fc, v_in, gamma, beta, out0);
}

// Round 5
// 434.333 us; speedup vs baseline: 1.0277x; 1.0277x over previous
//
#include <hip/hip_runtime.h>
#include <hip/hip_bf16.h>
#include <cstdint>
#include <cstddef>

typedef unsigned short u16;
typedef unsigned int u32;
typedef short v8s __attribute__((ext_vector_type(8)));   // 8 bf16 payloads (4 VGPRs)
typedef float v4f __attribute__((ext_vector_type(4)));
typedef __hip_bfloat16 bf16;

// B=4, N=1024, D=1024, H=8, DK=DV=128
#define PROJ_ELEMS  4194304ull        // 4096*1024
#define AT_ELEMS    33554432ull       // 4*8*1024*1024
#define INV_TEMP    0.08838834764831845f

#define GLOBAL_AS __attribute__((address_space(1)))
#define LDS_AS    __attribute__((address_space(3)))

__device__ __forceinline__ void store_out(float* p, float v) { *p = v; }
__device__ __forceinline__ void store_out(bf16* p, float v) { *p = __float2bfloat16(v); }

// load 8 contiguous fp32 elements, convert to bf16x8 fragment
__device__ __forceinline__ v8s load8f(const float* p) {
    const float4 a = *(const float4*)p;
    const float4 b = *(const float4*)(p + 4);
    v8s r;
    bf16 t;
    t = __float2bfloat16(a.x); r[0] = *(const short*)&t;
    t = __float2bfloat16(a.y); r[1] = *(const short*)&t;
    t = __float2bfloat16(a.z); r[2] = *(const short*)&t;
    t = __float2bfloat16(a.w); r[3] = *(const short*)&t;
    t = __float2bfloat16(b.x); r[4] = *(const short*)&t;
    t = __float2bfloat16(b.y); r[5] = *(const short*)&t;
    t = __float2bfloat16(b.z); r[6] = *(const short*)&t;
    t = __float2bfloat16(b.w); r[7] = *(const short*)&t;
    return r;
}

// ---------------------------------------------------------------------------
// MFMA GEMM core:  C[128x128 tile] = alpha * A[M,K] @ B[N,K]^T   (bf16 A/B)
// Staged via global_load_lds width=16 (m97 fast path), unpadded [128][32].
// ---------------------------------------------------------------------------
template <typename AT, typename OutT>
__device__ __forceinline__ void gemm_core(
    const AT* __restrict__ Ab, const u16* __restrict__ Bb, OutT* __restrict__ Cb,
    int K, int lda, int ldb, int ldc, float alpha, int m0, int n0)
{
    __shared__ __align__(16) u16 sA[128][32];
    __shared__ __align__(16) u16 sB[128][32];

    const int tid  = threadIdx.x;
    const int lane = tid & 63;
    const int wid  = tid >> 6;
    const int wm = (wid >> 1) * 64;
    const int wn = (wid & 1) * 64;
    const int quad = lane >> 4;
    const int l16  = lane & 15;

    v4f acc[4][4];
    #pragma unroll
    for (int i = 0; i < 4; ++i)
        #pragma unroll
        for (int j = 0; j < 4; ++j)
            acc[i][j] = (v4f){0.f, 0.f, 0.f, 0.f};

    for (int k0 = 0; k0 < K; k0 += 32) {
        #pragma unroll
        for (int it = 0; it < 2; ++it) {
            const int slot = tid + it * 256;
            const int row  = slot >> 2;
            const int cg   = (slot & 3) << 3;
            __builtin_amdgcn_global_load_lds(
                (const GLOBAL_AS void*)(Bb + (size_t)(n0 + row) * (size_t)ldb + (size_t)(k0 + cg)),
                (LDS_AS void*)((char*)&sB[0][0] + slot * 16), 16, 0, 0);
            if constexpr (sizeof(AT) == 2) {
                __builtin_amdgcn_global_load_lds(
                    (const GLOBAL_AS void*)((const u16*)Ab + (size_t)(m0 + row) * (size_t)lda + (size_t)(k0 + cg)),
                    (LDS_AS void*)((char*)&sA[0][0] + slot * 16), 16, 0, 0);
            } else {
                *(v8s*)&sA[row][cg] =
                    load8f((const float*)Ab + (size_t)(m0 + row) * (size_t)lda + (size_t)(k0 + cg));
            }
        }
        __syncthreads();

        v8s af[4], bfr[4];
        #pragma unroll
        for (int i = 0; i < 4; ++i) {
            af[i]  = *(const v8s*)&sA[wm + i * 16 + l16][quad * 8];
            bfr[i] = *(const v8s*)&sB[wn + i * 16 + l16][quad * 8];
        }
        #pragma unroll
        for (int i = 0; i < 4; ++i)
            #pragma unroll
            for (int j = 0; j < 4; ++j)
                acc[i][j] = __builtin_amdgcn_mfma_f32_16x16x32_bf16(af[i], bfr[j], acc[i][j], 0, 0, 0);
        __syncthreads();
    }

    // C/D layout (m89-verified): col = lane&15, row = quad*4 + reg
    #pragma unroll
    for (int i = 0; i < 4; ++i) {
        int rbase = m0 + wm + i * 16 + quad * 4;
        #pragma unroll
        for (int j = 0; j < 4; ++j) {
            int gcol = n0 + wn + j * 16 + l16;
            #pragma unroll
            for (int r = 0; r < 4; ++r)
                store_out(&Cb[(size_t)(rbase + r) * (size_t)ldc + (size_t)gcol],
                          acc[i][j][r] * alpha);
        }
    }
}

template <typename AT, typename OutT>
__global__ __launch_bounds__(256, 3)
void gemm_fast(const AT* __restrict__ A, const u16* __restrict__ B, OutT* __restrict__ C,
               int K, int lda, int ldb, int ldc, int batDiv,
               long long sAo, long long sAi, long long sBo, long long sBi,
               long long sCo, long long sCi, float alpha, int swz)
{
    const int z  = blockIdx.z;
    const int zo = z / batDiv;
    const int zi = z - zo * batDiv;
    int bx, by;
    if (swz) {
        // XCD-locality: blocks sharing an A row-panel (same by) land on one XCD.
        // requires gridDim.x == 8, gridDim.y == 32.
        const int flat = blockIdx.x + (blockIdx.y << 3);
        const int xcd = flat & 7, slt = flat >> 3;
        by = xcd + ((slt >> 3) << 3);
        bx = slt & 7;
    } else {
        bx = blockIdx.x; by = blockIdx.y;
    }
    gemm_core<AT, OutT>(A + (size_t)zo * (size_t)sAo + (size_t)zi * (size_t)sAi,
                        B + (size_t)zo * (size_t)sBo + (size_t)zi * (size_t)sBi,
                        C + (size_t)zo * (size_t)sCo + (size_t)zi * (size_t)sCi,
                        K, lda, ldb, ldc, alpha, by * 128, bx * 128);
}

// all five projections in one launch; XCD-locality swizzle groups the 8
// n-blocks sharing an A row-panel (plus the shared 2MB weight) on one XCD.
struct P5 { const u16* a[5]; };
__global__ __launch_bounds__(256, 3)
void gemm_proj5(P5 As, const u16* __restrict__ W, u16* __restrict__ C)
{
    const int fid = blockIdx.x + (blockIdx.y << 3) + (blockIdx.z << 8);
    const int xcd = fid & 7, s = fid >> 3;          // s in 0..159
    const int p = ((s >> 3) << 3) + xcd;            // pair index 0..159
    const int bx = s & 7;                           // n-tile
    const int by = p & 31;                          // m-tile (row panel)
    const int z  = p >> 5;                          // projection 0..4
    gemm_core<u16, bf16>(As.a[z], W + (size_t)z * 1048576ull,
                         (bf16*)(C + (size_t)z * PROJ_ELEMS),
                         1024, 1024, 1024, 1024, 1.f, by * 128, bx * 128);
}

// feature logits, split-K: grid (8 kc, 32 z); partial [z]128x128 over K=128
__global__ __launch_bounds__(256, 3)
void gemm_feat_sk(const u16* __restrict__ qfT, const u16* __restrict__ kfT, float* __restrict__ Fp)
{
    const int kc = blockIdx.x, z = blockIdx.y;
    gemm_core<u16, float>(qfT + (size_t)z * 131072ull + (size_t)kc * 128ull,
                          kfT + (size_t)z * 131072ull + (size_t)kc * 128ull,
                          Fp + ((size_t)kc * 32 + z) * 16384ull,
                          128, 1024, 1024, 128, INV_TEMP, 0, 0);
}

// ---------------------------------------------------------------------------
// fp32 -> bf16 unified converter + mask bit-pack:
// z 0..4 activations (2048 blocks), z 5..10 weights (512), z 11 mask (512).
// ---------------------------------------------------------------------------
struct CP11 { const float* p[11]; };

__global__ __launch_bounds__(256)
void cvt_all(CP11 ps, u16* __restrict__ actDst, u16* __restrict__ wDst,
             const int* __restrict__ mask, u32* __restrict__ mb)
{
    const int z = blockIdx.z;
    if (z == 11) {
        if (blockIdx.x >= 512) return;
        const int w = blockIdx.x * 256 + threadIdx.x;   // 131072 words
        const int* src = mask + (size_t)w * 32ull;
        u32 bits = 0;
        #pragma unroll
        for (int i = 0; i < 32; i += 4) {
            int4 v = *(const int4*)(src + i);
            bits |= (u32)(v.x != 0) << i;
            bits |= (u32)(v.y != 0) << (i + 1);
            bits |= (u32)(v.z != 0) << (i + 2);
            bits |= (u32)(v.w != 0) << (i + 3);
        }
        mb[w] = bits;
        return;
    }
    const int nblk = (z < 5) ? 2048 : 512;
    if (blockIdx.x >= nblk) return;
    const float* s = ps.p[z];
    u16* d = (z < 5) ? (actDst + (size_t)z * PROJ_ELEMS)
                     : (wDst + (size_t)(z - 5) * 1048576ull);
    const int i = (blockIdx.x * 256 + threadIdx.x) * 8;
    *(v8s*)(d + i) = load8f(s + i);
}

// ---------------------------------------------------------------------------
// Batched transpose of three projections: per z=(b*8+h) [1024 m][128 d] view
// -> [z][128 d][1024 m] contiguous.
// ---------------------------------------------------------------------------
struct T3 { const u16* in[3]; u16* out[3]; };
__global__ __launch_bounds__(256)
void transpose3(T3 t3)
{
    __shared__ u16 tile[32][33];
    const int sel = blockIdx.z >> 5;
    const int z   = blockIdx.z & 31;
    const int b = z >> 3, h = z & 7;
    const u16* ib = t3.in[sel] + (size_t)b * 1048576ull + (size_t)h * 128ull;
    u16* ob = t3.out[sel] + (size_t)z * 131072ull;
    const int m0 = blockIdx.x * 32;
    const int d0 = blockIdx.y * 32;
    const int tx = threadIdx.x;
    const int ty = threadIdx.y;
    #pragma unroll
    for (int i = 0; i < 4; ++i)
        tile[ty + i * 8][tx] = ib[(size_t)(m0 + ty + i * 8) * 1024ull + (size_t)(d0 + tx)];
    __syncthreads();
    #pragma unroll
    for (int i = 0; i < 4; ++i)
        ob[(size_t)(d0 + ty + i * 8) * 1024ull + (size_t)(m0 + tx)] = tile[tx][ty + i * 8];
}

// ---------------------------------------------------------------------------
// Fused attention v4 = r2/r3 main loops (measured best) + fused out2 epilogue:
//  - 512 threads / 8 waves, 128 Q-rows per block, KVBLK=128, 1 block/CU.
//  - wave owns 16 rows; softmax stats pure in-register butterfly shuffles.
//  - whole 32KB K/V tiles double-buffered, counted s_waitcnt vmcnt(N) + raw
//    s_barrier; vmcnt never drained to 0 in-loop (vmcnt(36) keeps prob
//    stores in flight across the pass-B head).
//  - XCD-locality swizzle: 8 m-tiles of one z on one XCD (L2-resident K/V).
//  - fused out2 epilogue: PV tile (128x128, complete per block) -> sQ-reuse
//    LDS, FT staged XOR-swizzled into sT, 32 MFMA/wave -> o2 directly.
// grid (8 m-tiles, 32 z), block 512.  LDS 140 KB.
// ---------------------------------------------------------------------------
__global__ __launch_bounds__(512, 2)
void fused_attn(const u16* __restrict__ qt, const u16* __restrict__ kt,
                const u16* __restrict__ vvT, const u32* __restrict__ mb,
                const u16* __restrict__ FTg,
                float* __restrict__ oAT, u16* __restrict__ o2)
{
    __shared__ __align__(16) u16 sQ[4][128][32];       // resident Q tile, 32 KB
    __shared__ __align__(16) u16 sT[2][4][128][32];    // staging dbuf, 64 KB
    __shared__ __align__(16) u16 sP[4][128][40];       // bf16 probs, padded, 40 KB
    __shared__ u32 smw[2][128][4];                     // mask words dbuf, 4 KB

    // XCD-locality remap: all 8 m-tiles of a z share one XCD.
    const int flat = blockIdx.x + (blockIdx.y << 3);
    const int xcd = flat & 7, slt = flat >> 3;
    const int z  = xcd + ((slt >> 3) << 3);
    const int m0 = (slt & 7) << 7;

    const int b = z >> 3, h = z & 7;
    const u16* qb = qt + (size_t)b * 1048576ull + (size_t)h * 128ull;
    const u16* kb = kt + (size_t)b * 1048576ull + (size_t)h * 128ull;
    const u16* vb = vvT + (size_t)z * 131072ull;
    float* Ob = oAT + (size_t)z * 1048576ull;
    const u32* mbb = mb + (size_t)b * 32768ull;

    const int tid = threadIdx.x;
    const int lane = tid & 63, wid = tid >> 6;         // 8 waves
    const int quad = lane >> 4, l16 = lane & 15;
    const int wm = wid << 4;                           // wave's 16-row slice

    // ---- staging: issue-only; waits at call sites (counted vmcnt) ----
    auto stK = [&](int nt, int buf) {                  // 4 x 16B per thread
        #pragma unroll
        for (int it = 0; it < 4; ++it) {
            const int s2 = tid + it * 512;             // 0..2047
            const int ks = s2 >> 9, row = (s2 >> 2) & 127, cg = (s2 & 3) << 3;
            __builtin_amdgcn_global_load_lds(
                (const GLOBAL_AS void*)(kb + (size_t)(nt * 128 + row) * 1024ull + ks * 32 + cg),
                (LDS_AS void*)((char*)&sT[buf][0][0][0] + s2 * 16), 16, 0, 0);
        }
    };
    auto stV = [&](int nt, int buf) {                  // 4 x 16B per thread
        #pragma unroll
        for (int it = 0; it < 4; ++it) {
            const int s2 = tid + it * 512;
            const int ks = s2 >> 9, row = (s2 >> 2) & 127, cg = (s2 & 3) << 3;
            __builtin_amdgcn_global_load_lds(
                (const GLOBAL_AS void*)(vb + (size_t)row * 1024ull + nt * 128 + ks * 32 + cg),
                (LDS_AS void*)((char*)&sT[buf][0][0][0] + s2 * 16), 16, 0, 0);
        }
    };
    auto stM = [&](int nt, int buf) {                  // 1 x 4B per thread (512 words)
        const int W = tid;                             // word index == row*4 + w
        __builtin_amdgcn_global_load_lds(
            (const GLOBAL_AS void*)(mbb + (size_t)(m0 + (W >> 2)) * 32ull + nt * 4 + (W & 3)),
            (LDS_AS void*)((char*)&smw[buf][0][0] + W * 4), 4, 0, 0);
    };

    // ---- prologue: Q (4) + K0 (4) + m0 (1) per thread in flight ----
    #pragma unroll
    for (int it = 0; it < 4; ++it) {
        const int s2 = tid + it * 512;
        const int ks = s2 >> 9, row = (s2 >> 2) & 127, cg = (s2 & 3) << 3;
        __builtin_amdgcn_global_load_lds(
            (const GLOBAL_AS void*)(qb + (size_t)(m0 + row) * 1024ull + ks * 32 + cg),
            (LDS_AS void*)((char*)&sQ[0][0][0] + s2 * 16), 16, 0, 0);
    }
    stK(0, 0); stM(0, 0);

    float Mreg[4], Lreg[4];                            // per-lane stats, 4 rows
    #pragma unroll
    for (int x = 0; x < 4; ++x) { Mreg[x] = -3.0e38f; Lreg[x] = 0.f; }

    // ---------------- PASS A: row max M and row sum L ----------------
    int bufA = 0, mcur = 0;
    for (int nt = 0; nt < 8; ++nt) {
        stK((nt + 1) & 7, bufA ^ 1);                   // nt=7 stages K0 for pass B
        stM((nt + 1) & 7, mcur ^ 1);
        asm volatile("s_waitcnt vmcnt(5)" ::: "memory");   // K_nt + m_nt landed; 5 in flight
        __builtin_amdgcn_s_barrier();
        __builtin_amdgcn_sched_barrier(0);

        v4f acc[8];
        #pragma unroll
        for (int j = 0; j < 8; ++j)
            acc[j] = (v4f){0.f, 0.f, 0.f, 0.f};
        #pragma unroll
        for (int ks = 0; ks < 4; ++ks) {
            const v8s aq = *(const v8s*)&sQ[ks][wm + l16][quad * 8];
            v8s bk[8];
            #pragma unroll
            for (int j = 0; j < 8; ++j)
                bk[j] = *(const v8s*)&sT[bufA][ks][j * 16 + l16][quad * 8];
            #pragma unroll
            for (int j = 0; j < 8; ++j)
                acc[j] = __builtin_amdgcn_mfma_f32_16x16x32_bf16(aq, bk[j], acc[j], 0, 0, 0);
        }

        // in-register masked online stats (rows exclusive to this wave)
        #pragma unroll
        for (int r = 0; r < 4; ++r) {
            const int rowl = wm + quad * 4 + r;
            const u32 mw0 = smw[mcur][rowl][0];
            const u32 mw1 = smw[mcur][rowl][1];
            const u32 mw2 = smw[mcur][rowl][2];
            const u32 mw3 = smw[mcur][rowl][3];
            float sv[8];
            float tmax = -3.0e38f;
            #pragma unroll
            for (int j = 0; j < 8; ++j) {
                const u32 word = (j < 2) ? mw0 : (j < 4) ? mw1 : (j < 6) ? mw2 : mw3;
                const int bit = ((j & 1) << 4) + l16;
                float s = acc[j][r] * INV_TEMP;
                s = ((word >> bit) & 1u) ? s : -1e9f;
                sv[j] = s;
                tmax = fmaxf(tmax, s);
            }
            #pragma unroll
            for (int m = 1; m <= 8; m <<= 1)
                tmax = fmaxf(tmax, __shfl_xor(tmax, m));
            const float Mo = Mreg[r];
            const float Mn = fmaxf(Mo, tmax);
            float t = 0.f;
            #pragma unroll
            for (int j = 0; j < 8; ++j)
                t += __expf(sv[j] - Mn);
            #pragma unroll
            for (int m = 1; m <= 8; m <<= 1)
                t += __shfl_xor(t, m);
            Lreg[r] = Lreg[r] * __expf(Mo - Mn) + t;
            Mreg[r] = Mn;
        }

        asm volatile("s_waitcnt lgkmcnt(0)" ::: "memory");
        __builtin_amdgcn_s_barrier();                  // sT[bufA] free for restage
        __builtin_amdgcn_sched_barrier(0);
        bufA ^= 1; mcur ^= 1;
    }

    float IL[4];
    #pragma unroll
    for (int x = 0; x < 4; ++x) IL[x] = 1.f / Lreg[x];

    const int BK = bufA;                               // holds K0 (after 8 flips == 0)
    const int BV = BK ^ 1;

    v4f pacc[8];
    #pragma unroll
    for (int j = 0; j < 8; ++j)
        pacc[j] = (v4f){0.f, 0.f, 0.f, 0.f};

    // ---------------- PASS B: probs out + PV accumulate ----------------
    for (int nt = 0; nt < 8; ++nt) {
        stV(nt, BV);                                   // V_nt in flight (4)
        if (nt == 0) {
            asm volatile("s_waitcnt vmcnt(4)" ::: "memory");   // K_0 + m_0 landed
        } else {
            // in-order vmcnt: 32 prob stores + 4 stV issued after K_nt/m_nt ->
            // vmcnt(36) proves the loads landed WITHOUT draining the stores.
            asm volatile("s_waitcnt vmcnt(36)" ::: "memory");
        }
        __builtin_amdgcn_s_barrier();
        __builtin_amdgcn_sched_barrier(0);

        v4f acc[8];
        #pragma unroll
        for (int j = 0; j < 8; ++j)
            acc[j] = (v4f){0.f, 0.f, 0.f, 0.f};
        #pragma unroll
        for (int ks = 0; ks < 4; ++ks) {
            const v8s aq = *(const v8s*)&sQ[ks][wm + l16][quad * 8];
            v8s bk[8];
            #pragma unroll
            for (int j = 0; j < 8; ++j)
                bk[j] = *(const v8s*)&sT[BK][ks][j * 16 + l16][quad * 8];
            #pragma unroll
            for (int j = 0; j < 8; ++j)
                acc[j] = __builtin_amdgcn_mfma_f32_16x16x32_bf16(aq, bk[j], acc[j], 0, 0, 0);
        }

        asm volatile("s_waitcnt lgkmcnt(0)" ::: "memory");
        __builtin_amdgcn_s_barrier();                  // all waves done reading sT[BK]
        __builtin_amdgcn_sched_barrier(0);

        if (nt < 7) {
            stK(nt + 1, BK);                           // prefetch next K under softmax+PV
            stM(nt + 1, mcur ^ 1);
            asm volatile("s_waitcnt vmcnt(5)" ::: "memory");  // V_nt done; K_{nt+1}+m in flight
        } else {
            asm volatile("s_waitcnt vmcnt(0)" ::: "memory");  // tail: drain everything
        }

        // probs: fp32 to oAT + bf16 into padded sP
        #pragma unroll
        for (int r = 0; r < 4; ++r) {
            const int rowl = wm + quad * 4 + r;
            const u32 mw0 = smw[mcur][rowl][0];
            const u32 mw1 = smw[mcur][rowl][1];
            const u32 mw2 = smw[mcur][rowl][2];
            const u32 mw3 = smw[mcur][rowl][3];
            float* orow = Ob + (size_t)(m0 + rowl) * 1024ull + nt * 128;
            #pragma unroll
            for (int j = 0; j < 8; ++j) {
                const u32 word = (j < 2) ? mw0 : (j < 4) ? mw1 : (j < 6) ? mw2 : mw3;
                const int bit = ((j & 1) << 4) + l16;
                float s = acc[j][r] * INV_TEMP;
                s = ((word >> bit) & 1u) ? s : -1e9f;
                const float p = __expf(s - Mreg[r]) * IL[r];
                orow[j * 16 + l16] = p;
                bf16 pb = __float2bfloat16(p);
                sP[j >> 1][rowl][((j & 1) << 4) + l16] = *(const u16*)&pb;
            }
        }

        asm volatile("s_waitcnt lgkmcnt(0)" ::: "memory");
        __builtin_amdgcn_s_barrier();                  // sP visible; sT[BV] ready
        __builtin_amdgcn_sched_barrier(0);

        #pragma unroll
        for (int ks = 0; ks < 4; ++ks) {
            const v8s ap = *(const v8s*)&sP[ks][wm + l16][quad * 8];
            v8s bv[8];
            #pragma unroll
            for (int j = 0; j < 8; ++j)
                bv[j] = *(const v8s*)&sT[BV][ks][j * 16 + l16][quad * 8];
            #pragma unroll
            for (int j = 0; j < 8; ++j)
                pacc[j] = __builtin_amdgcn_mfma_f32_16x16x32_bf16(ap, bv[j], pacc[j], 0, 0, 0);
        }

        asm volatile("s_waitcnt lgkmcnt(0)" ::: "memory");
        __builtin_amdgcn_s_barrier();                  // sT[BV] free for next stV
        __builtin_amdgcn_sched_barrier(0);
        mcur ^= 1;
    }

    // ---------------- fused out2 epilogue: o2 = (P@V) @ AF ----------------
    // sPV reuses sQ (32 KB, [4 ks][128][32]); sFT reuses sT (32 KB, XOR-swizzled).
    // All pending vmem drained (tail vmcnt(0)); all LDS reads done (last barrier).
    u16* sPVp = &sQ[0][0][0];
    u16* sFTp = &sT[0][0][0][0];
    const u16* FTz = FTg + (size_t)z * 16384ull;

    #pragma unroll
    for (int j = 0; j < 8; ++j) {
        const int c = j * 16 + l16;
        #pragma unroll
        for (int r = 0; r < 4; ++r) {
            const int rowl = wm + quad * 4 + r;
            bf16 pb = __float2bfloat16(pacc[j][r]);
            sPVp[(c >> 5) * 4096 + rowl * 32 + (c & 31)] = *(const u16*)&pb;
        }
    }
    #pragma unroll
    for (int rep = 0; rep < 4; ++rep) {                // FT: 2048 groups of 8 u16
        const int grp = tid + rep * 512;
        const int row = grp >> 4;                      // e index (256B rows)
        v8s v = *(const v8s*)(FTz + (size_t)grp * 8ull);
        *(v8s*)((char*)sFTp + ((grp * 16) ^ ((row & 7) << 4))) = v;
    }
    asm volatile("s_waitcnt lgkmcnt(0)" ::: "memory");
    __builtin_amdgcn_s_barrier();
    __builtin_amdgcn_sched_barrier(0);

    v4f o2a[8];
    #pragma unroll
    for (int j = 0; j < 8; ++j)
        o2a[j] = (v4f){0.f, 0.f, 0.f, 0.f};
    #pragma unroll
    for (int ks = 0; ks < 4; ++ks) {
        const v8s ap2 = *(const v8s*)&sPVp[ks * 4096 + (wm + l16) * 32 + quad * 8];
        #pragma unroll
        for (int j = 0; j < 8; ++j) {
            const int rowf = j * 16 + l16;
            const v8s bft = *(const v8s*)((char*)sFTp +
                ((rowf * 256 + ks * 64 + quad * 16) ^ ((rowf & 7) << 4)));
            o2a[j] = __builtin_amdgcn_mfma_f32_16x16x32_bf16(ap2, bft, o2a[j], 0, 0, 0);
        }
    }

    u16* o2B = o2 + (size_t)b * 1048576ull + (size_t)h * 128ull;
    #pragma unroll
    for (int j = 0; j < 8; ++j) {
        const int c = j * 16 + l16;
        #pragma unroll
        for (int r = 0; r < 4; ++r) {
            const int m = m0 + wm + quad * 4 + r;
            bf16 t = __float2bfloat16(o2a[j][r]);
            o2B[(size_t)m * 1024ull + c] = *(const u16*)&t;
        }
    }
}

// ---------------------------------------------------------------------------
// Feature softmax with split-K reduction: Fp [8 kc][32 z][128 d][128 e] ->
// softmax rows -> fp32 attn_feature output AND transposed bf16 FT[z][e][d].
// ---------------------------------------------------------------------------
__global__ __launch_bounds__(128)
void softmax_feat(const float* __restrict__ Fp, float* __restrict__ out_af, u16* __restrict__ FT)
{
    const int r = blockIdx.x;
    const int z = r >> 7, d = r & 127;
    const int e = threadIdx.x;
    float x = 0.f;
    #pragma unroll
    for (int kc = 0; kc < 8; ++kc)
        x += Fp[((size_t)kc * 32 + z) * 16384ull + (size_t)d * 128ull + e];
    float mx = x;
    #pragma unroll
    for (int o = 32; o; o >>= 1) mx = fmaxf(mx, __shfl_xor(mx, o));
    __shared__ float redm[2], reds[2];
    const int w = e >> 6;
    if ((e & 63) == 0) redm[w] = mx;
    __syncthreads();
    mx = fmaxf(redm[0], redm[1]);
    float ex = __expf(x - mx);
    float s = ex;
    #pragma unroll
    for (int o = 32; o; o >>= 1) s += __shfl_xor(s, o);
    if ((e & 63) == 0) reds[w] = s;
    __syncthreads();
    s = reds[0] + reds[1];
    float p = ex / s;
    out_af[(size_t)r * 128ull + e] = p;
    bf16 pb = __float2bfloat16(p);
    FT[(size_t)z * 16384ull + (size_t)e * 128ull + d] = *(const u16*)&pb;
}

// ---------------------------------------------------------------------------
// out = LayerNorm(fc + v) * gamma + beta ; one block per row; float4 loads
// ---------------------------------------------------------------------------
__global__ __launch_bounds__(256)
void resid_ln(const float* __restrict__ fc, const float* __restrict__ v,
              const float* __restrict__ gamma, const float* __restrict__ beta,
              float* __restrict__ out)
{
    const int r = blockIdx.x;
    const int t = threadIdx.x;
    const float4* fr = (const float4*)(fc + (size_t)r * 1024ull);
    const float4* vr = (const float4*)(v  + (size_t)r * 1024ull);
    float4 a = fr[t], b4 = vr[t];
    float4 x = {a.x + b4.x, a.y + b4.y, a.z + b4.z, a.w + b4.w};
    float s  = x.x + x.y + x.z + x.w;
    float s2 = x.x * x.x + x.y * x.y + x.z * x.z + x.w * x.w;
    #pragma unroll
    for (int o = 32; o; o >>= 1) { s += __shfl_xor(s, o); s2 += __shfl_xor(s2, o); }
    __shared__ float rs[4], rs2[4];
    const int w = t >> 6;
    if ((t & 63) == 0) { rs[w] = s; rs2[w] = s2; }
    __syncthreads();
    s  = rs[0] + rs[1] + rs[2] + rs[3];
    s2 = rs2[0] + rs2[1] + rs2[2] + rs2[3];
    const float mean = s * (1.f / 1024.f);
    const float var  = s2 * (1.f / 1024.f) - mean * mean;
    const float rstd = rsqrtf(var + 1e-6f);
    const float4 g = ((const float4*)gamma)[t];
    const float4 bb = ((const float4*)beta)[t];
    float4 o4 = {(x.x - mean) * rstd * g.x + bb.x,
                 (x.y - mean) * rstd * g.y + bb.y,
                 (x.z - mean) * rstd * g.z + bb.z,
                 (x.w - mean) * rstd * g.w + bb.w};
    ((float4*)(out + (size_t)r * 1024ull))[t] = o4;
}

// ---------------------------------------------------------------------------
extern "C" void kernel_launch(void* const* d_in, const int* in_sizes, int n_in,
                              void* d_out, int out_size, void* d_ws, size_t ws_size,
                              hipStream_t stream)
{
    (void)in_sizes; (void)n_in; (void)out_size; (void)ws_size;
    const float* q_time    = (const float*)d_in[0];
    const float* k_time    = (const float*)d_in[1];
    const float* q_feature = (const float*)d_in[2];
    const float* k_feature = (const float*)d_in[3];
    const float* v_in      = (const float*)d_in[4];
    const int*   mask      = (const int*)d_in[5];
    const float* w_qs_t    = (const float*)d_in[6];
    const float* w_ks_t    = (const float*)d_in[7];
    const float* w_qs_f    = (const float*)d_in[8];
    const float* w_ks_f    = (const float*)d_in[9];
    const float* w_vs      = (const float*)d_in[10];
    const float* w_fc      = (const float*)d_in[11];
    const float* gamma     = (const float*)d_in[12];
    const float* beta      = (const float*)d_in[13];

    // workspace layout (93 MB peak; liveness-aliased):
    //  0..40   act (5x8MB)              [dead after proj5]
    // 40..52   wbf (6x2MB; wfc 50..52 alive until fc)
    // 52..92   qt,kt,qf,kf,vv (5x8MB)   [qf,kf dead after transpose3; vv after transpose3;
    //                                    qt,kt dead after fused_attn]
    //  0..8    vvT    (aliases act)
    //  8..16   qfT
    // 16..24   kfT
    // 24..25   FT
    // 25..41   Fp (8x2MB fp32 partials)
    // 41..49   o2  (written by fused_attn epilogue; aliases dead wbf[41..49]/act)
    // 60..76   fc  (aliases dead kt,qf)
    // 92..92.5 mb  (mask bits, virgin region)
    char* ws = (char*)d_ws;
    const size_t MB = 1ull << 20;
    u16*   act = (u16*)(ws + 0  * MB);
    u16*   wbf = (u16*)(ws + 40 * MB);
    u16*   qt  = (u16*)(ws + 52 * MB);
    u16*   vvT = (u16*)(ws + 0  * MB);
    u16*   qfT = (u16*)(ws + 8  * MB);
    u16*   kfT = (u16*)(ws + 16 * MB);
    u16*   FT  = (u16*)(ws + 24 * MB);
    float* Fp  = (float*)(ws + 25 * MB);
    u16*   o2  = (u16*)(ws + 41 * MB);
    float* fc  = (float*)(ws + 60 * MB);
    u32*   mb  = (u32*)(ws + 92 * MB);
    u16*   kt  = qt + PROJ_ELEMS;
    u16*   qf  = kt + PROJ_ELEMS;
    u16*   kf  = qf + PROJ_ELEMS;
    u16*   vv  = kf + PROJ_ELEMS;
    u16*   wfc = wbf + 5ull * 1048576ull;

    float* out0 = (float*)d_out;
    float* oAT  = out0 + PROJ_ELEMS;              // attn_time [4,8,1024,1024] fp32
    float* oAF  = out0 + PROJ_ELEMS + AT_ELEMS;   // attn_feature [4,8,128,128] fp32

    const dim3 blk(256);

    // 0) fp32 -> bf16 conversions + mask bit-pack, one launch
    {
        CP11 ca;
        ca.p[0] = q_time; ca.p[1] = k_time; ca.p[2] = q_feature;
        ca.p[3] = k_feature; ca.p[4] = v_in;
        ca.p[5] = w_qs_t; ca.p[6] = w_ks_t; ca.p[7] = w_qs_f;
        ca.p[8] = w_ks_f; ca.p[9] = w_vs; ca.p[10] = w_fc;
        cvt_all<<<dim3(2048, 1, 12), blk, 0, stream>>>(ca, act, wbf, mask, mb);
    }

    // 1) five projections, one launch (XCD-swizzled)
    {
        P5 ps; for (int i = 0; i < 5; ++i) ps.a[i] = act + (size_t)i * PROJ_ELEMS;
        gemm_proj5<<<dim3(8, 32, 5), blk, 0, stream>>>(ps, wbf, qt);
    }

    // 2) transposes vv,qf,kf -> vvT,qfT,kfT
    {
        T3 t3; t3.in[0] = vv; t3.in[1] = qf; t3.in[2] = kf;
               t3.out[0] = vvT; t3.out[1] = qfT; t3.out[2] = kfT;
        transpose3<<<dim3(32, 4, 96), dim3(32, 8, 1), 0, stream>>>(t3);
    }

    // 3) feature logits (split-K x8) -> Fp partials
    gemm_feat_sk<<<dim3(8, 32), blk, 0, stream>>>(qfT, kfT, Fp);

    // 4) feature softmax (+split-K reduce) -> oAF fp32 + FT bf16
    softmax_feat<<<4096, 128, 0, stream>>>(Fp, oAF, FT);

    // 5) fused attention: logits+mask+softmax -> oAT fp32; (P@V)@AF -> o2 bf16
    fused_attn<<<dim3(8, 32), dim3(512), 0, stream>>>(qt, kt, vvT, mb, FT, oAT, o2);

    // 6) fc: o2(bf16) @ w_fc(bf16)^T -> fp32 (XCD-swizzled)
    gemm_fast<<<dim3(8, 32, 1), blk, 0, stream>>>(o2, wfc, fc, 1024, 1024, 1024, 1024, 1,
        0LL, 0LL, 0LL, 0LL, 0LL, 0LL, 1.f, 1);

    // 7) residual + LayerNorm -> out0
    resid_ln<<<4096, 256, 0, stream>>>(fc, v_in, gamma, beta, out0);
}